// Round 19
// baseline (50.871 us; speedup 1.0000x reference)
//
#include <hip/hip_runtime.h>

// Problem constants: B=8, S=2048, D=512, G=2, V=320, CV=128
#define M_ROWS 16384   // B*S
#define K_DIM  512
#define N_COLS 640     // G*V
#define V_CODES 320
#define CV_DIM 128

typedef _Float16 half8 __attribute__((ext_vector_type(8)));
typedef _Float16 half4v __attribute__((ext_vector_type(4)));
typedef float floatx4 __attribute__((ext_vector_type(4)));

__device__ inline void gll16(const void* g, void* l) {
    __builtin_amdgcn_global_load_lds(
        (const __attribute__((address_space(1))) void*)g,
        (__attribute__((address_space(3))) void*)l, 16, 0, 0);
}

#define SBAR()  __builtin_amdgcn_sched_barrier(0)
#define WAITV(N) asm volatile("s_waitcnt vmcnt(" #N ")" ::: "memory")
#define WAITL() asm volatile("s_waitcnt lgkmcnt(0)" ::: "memory")

// ---------------------------------------------------------------------------
// Kernel 0: prepW — LDS-tiled transpose W (512,640) f32 -> Wt (640,512) f16;
// block 320 zeroes the global marginal.
// ---------------------------------------------------------------------------
__global__ __launch_bounds__(256)
void prepW(const float* __restrict__ W, _Float16* __restrict__ Wt,
           float* __restrict__ marginal) {
    __shared__ float tile[32][33];
    const int b = blockIdx.x, t = threadIdx.x;
    if (b == 320) {
        for (int i = t; i < 640; i += 256) marginal[i] = 0.f;
        return;
    }
    const int n0 = (b % 20) * 32, k0 = (b / 20) * 32;
    {
        const int kk = t >> 3, nn4 = (t & 7) << 2;
        const float4 w = *(const float4*)(W + (size_t)(k0 + kk) * 640 + n0 + nn4);
        tile[kk][nn4 + 0] = w.x; tile[kk][nn4 + 1] = w.y;
        tile[kk][nn4 + 2] = w.z; tile[kk][nn4 + 3] = w.w;
    }
    __syncthreads();
    {
        const int nn = t >> 3, kk4 = (t & 7) << 2;
        half4v h = {(_Float16)tile[kk4 + 0][nn], (_Float16)tile[kk4 + 1][nn],
                    (_Float16)tile[kk4 + 2][nn], (_Float16)tile[kk4 + 3][nn]};
        *(half4v*)(Wt + (size_t)(n0 + nn) * 512 + k0 + kk4) = h;
    }
}

// ---------------------------------------------------------------------------
// Fused kernel = round-15 pipeline at DOUBLE TLP: 512 threads = 8 waves,
// wave (mi=w>>1, nh=w&1) owns 16 rows x 160 cols (acc[10]). Same total LDS
// traffic and 48 KB LDS as r15 -> 2 blocks/CU = 16 waves/CU (was 8).
// B-staging: 1280 chunks / 512 threads -> waves 0-3 do 3 gll16, waves 4-7
// do 2; counted waits are per-wave exact (newest tile = A(1)+B(3|2)).
// Epilogue: per-row partials over 160 cols -> LDS cross-nh combine ->
// marginal atomics + in-kernel cv gather / out writes.
// ---------------------------------------------------------------------------
__global__ __launch_bounds__(512, 4)
void fused(const float* __restrict__ A, const _Float16* __restrict__ Bt,
           const float* __restrict__ bias, const float* __restrict__ gum,
           const float* __restrict__ cv, float* __restrict__ out,
           float* __restrict__ marginal) {
    __shared__ _Float16 Bs[2][320 * 32];   // 2 x 20 KB
    __shared__ _Float16 As[2][64 * 32];    // 2 x 4 KB
    __shared__ float smarg[320];
    __shared__ float wbest[2][64];
    __shared__ float wsum[2][64];
    __shared__ int   wbidx[2][64];
    __shared__ int   fbidx[64];
    __shared__ float finv[64];

    const int t = threadIdx.x;
    const int wave = t >> 6, lane = t & 63;
    const int bm = blockIdx.x, g = blockIdx.y;
    const int mi = wave >> 1, nh = wave & 1;
    const int c = lane & 15, kq = lane >> 4;

    for (int i = t; i < 320; i += 512) smarg[i] = 0.f;

    floatx4 acc[10];
#pragma unroll
    for (int nt = 0; nt < 10; ++nt) acc[nt] = (floatx4){0.f, 0.f, 0.f, 0.f};

    // A staging: row am = t>>3, float4-slot ad = t&7; chunk = ad>>1, ^(am&3)
    const int am = t >> 3, ad = t & 7;
    const int a_wr = am * 64 + ((((ad >> 1) ^ (am & 3))) << 4) + (ad & 1) * 8;
    const float* Aptr = A + (size_t)(bm * 64 + am) * 512 + ad * 4;

    const _Float16* Bg = Bt + (size_t)g * V_CODES * K_DIM;

    float4 avA, avN;

    auto ISSUE_B = [&](int buf, int k0) {
        {
            const int q = t;                          // 0..511
            const int n = q >> 2, j = q & 3;
            gll16(Bg + (size_t)n * 512 + k0 + ((j ^ (n & 3)) << 3),
                  (char*)(&Bs[buf][0]) + q * 16);
        }
        {
            const int q = t + 512;                    // 512..1023
            const int n = q >> 2, j = q & 3;
            gll16(Bg + (size_t)n * 512 + k0 + ((j ^ (n & 3)) << 3),
                  (char*)(&Bs[buf][0]) + q * 16);
        }
        if (t < 256) {                                // waves 0-3 full
            const int q = t + 1024;                   // 1024..1279
            const int n = q >> 2, j = q & 3;
            gll16(Bg + (size_t)n * 512 + k0 + ((j ^ (n & 3)) << 3),
                  (char*)(&Bs[buf][0]) + q * 16);
        }
    };
    auto WRITE_A = [&](int buf, const float4& v) {
        const half4v h = {(_Float16)v.x, (_Float16)v.y, (_Float16)v.z,
                          (_Float16)v.w};
        *(half4v*)((char*)(&As[buf][0]) + a_wr) = h;
    };
    auto COMPUTE = [&](int cur) {
        const int ra = mi * 16 + c;
        const half8 af = *(const half8*)((const char*)(&As[cur][0]) +
                          ra * 64 + ((kq ^ (ra & 3)) << 4));
        __builtin_amdgcn_s_setprio(1);
#pragma unroll
        for (int nt = 0; nt < 10; ++nt) {
            const int rb = nh * 160 + nt * 16 + c;
            const half8 bf = *(const half8*)((const char*)(&Bs[cur][0]) +
                              rb * 64 + ((kq ^ (rb & 3)) << 4));
            acc[nt] = __builtin_amdgcn_mfma_f32_16x16x32_f16(af, bf, acc[nt], 0, 0, 0);
        }
        __builtin_amdgcn_s_setprio(0);
    };
    auto WAITPW = [&]() {   // per-wave counted wait: newest tile stays in flight
        if (wave < 4) { WAITV(4); } else { WAITV(3); }
    };

    // ---- prologue: tiles 0 and 1 ----
    avA = *(const float4*)(Aptr + 0);
    ISSUE_B(0, 0);
    WRITE_A(0, avA);                 // compiler waits only the A(0) load
    ISSUE_B(1, 32);
    avA = *(const float4*)(Aptr + 32);
    SBAR(); WAITPW();                // tile0's B done; tile1 stays in flight
    SBAR(); WAITL();
    SBAR(); __builtin_amdgcn_s_barrier(); SBAR();

    // ---- steady state: kt = 0..13 ----
    for (int kt = 0; kt < 14; ++kt) {
        const int cur = kt & 1;
        COMPUTE(cur);
        SBAR(); __builtin_amdgcn_s_barrier(); SBAR();   // readers of cur done
        ISSUE_B(cur, (kt + 2) * 32);                    // tile kt+2 -> cur
        avN = *(const float4*)(Aptr + (kt + 2) * 32);
        WRITE_A(cur ^ 1, avA);                          // A of tile kt+1
        SBAR(); WAITPW();                               // tile kt+1's B done
        SBAR(); WAITL();
        SBAR(); __builtin_amdgcn_s_barrier(); SBAR();
        avA = avN;
    }
    // ---- kt = 14 ----
    COMPUTE(0);
    SBAR(); __builtin_amdgcn_s_barrier(); SBAR();
    WRITE_A(1, avA);                                    // A of tile 15
    SBAR(); WAITV(0);                                   // drain tile 15's B
    SBAR(); WAITL();
    SBAR(); __builtin_amdgcn_s_barrier(); SBAR();
    // ---- kt = 15 ----
    COMPUTE(1);

    // ---- epilogue ----
    float bcol[10];
#pragma unroll
    for (int nt = 0; nt < 10; ++nt)
        bcol[nt] = bias[g * V_CODES + nh * 160 + nt * 16 + c];

    // pass 1: per-rg row partials over this wave's 160 cols
#pragma unroll
    for (int rg = 0; rg < 4; ++rg) {
        const int row = mi * 16 + kq * 4 + rg;          // block-local row
        const float* gr = gum + ((size_t)(bm * 64 + row) * 2 + g) * V_CODES
                          + nh * 160 + c;
        float lg[10];
#pragma unroll
        for (int nt = 0; nt < 10; ++nt) lg[nt] = acc[nt][rg] + bcol[nt];
        float best = -1e30f; int bidx = 0;
#pragma unroll
        for (int nt = 0; nt < 10; ++nt) {
            const float nz = lg[nt] + gr[nt * 16];
            const int v = nh * 160 + nt * 16 + c;       // group-local col
            if (nz > best) { best = nz; bidx = v; }
        }
#pragma unroll
        for (int mask = 1; mask <= 8; mask <<= 1) {
            const float ob = __shfl_xor(best, mask);
            const int   oi = __shfl_xor(bidx, mask);
            if (ob > best || (ob == best && oi < bidx)) { best = ob; bidx = oi; }
        }
        float s = 0.f;
#pragma unroll
        for (int nt = 0; nt < 10; ++nt) {
            const float e = __expf(lg[nt]);
            acc[nt][rg] = e;                            // keep exp
            s += e;
        }
#pragma unroll
        for (int mask = 1; mask <= 8; mask <<= 1) s += __shfl_xor(s, mask);
        if (c == 0) {
            wbest[nh][row] = best;
            wbidx[nh][row] = bidx;
            wsum[nh][row]  = s;
        }
    }
    __syncthreads();

    // cross-nh combine: final argmax + 1/sum per row
    if (t < 64) {
        const float b0 = wbest[0][t]; const int i0 = wbidx[0][t];
        const float b1 = wbest[1][t]; const int i1 = wbidx[1][t];
        fbidx[t] = (b1 > b0 || (b1 == b0 && i1 < i0)) ? i1 : i0;
        finv[t]  = 1.f / (wsum[0][t] + wsum[1][t]);
    }
    __syncthreads();

    // marginal: sum exp*inv over this wave's 16 rows
    float mcon[10];
#pragma unroll
    for (int nt = 0; nt < 10; ++nt) mcon[nt] = 0.f;
#pragma unroll
    for (int rg = 0; rg < 4; ++rg) {
        const float iv = finv[mi * 16 + kq * 4 + rg];
#pragma unroll
        for (int nt = 0; nt < 10; ++nt) mcon[nt] += acc[nt][rg] * iv;
    }
#pragma unroll
    for (int nt = 0; nt < 10; ++nt) {
        mcon[nt] += __shfl_xor(mcon[nt], 16);
        mcon[nt] += __shfl_xor(mcon[nt], 32);
    }
    if (lane < 16) {
#pragma unroll
        for (int nt = 0; nt < 10; ++nt)
            atomicAdd(&smarg[nh * 160 + nt * 16 + c], mcon[nt]);
    }
    __syncthreads();
    for (int i = t; i < 320; i += 512)
        atomicAdd(marginal + g * V_CODES + i, smarg[i]);

    // out: nh==0 waves write their mi's 16 rows (8 lanes/row x 64B)
    if (nh == 0) {
#pragma unroll
        for (int rr = 0; rr < 2; ++rr) {
            const int row = mi * 16 + rr * 8 + (lane >> 3);
            const int bi = fbidx[row];
            const int p = lane & 7;
            const float4* cvp = (const float4*)(cv +
                ((size_t)g * V_CODES + bi) * CV_DIM) + p * 4;
            const float4 v0 = cvp[0], v1 = cvp[1], v2 = cvp[2], v3 = cvp[3];
            float4* op = (float4*)(out + (size_t)(bm * 64 + row) * 256
                                   + g * CV_DIM) + p * 4;
            op[0] = v0; op[1] = v1; op[2] = v2; op[3] = v3;
        }
    }
}

// ---------------------------------------------------------------------------
// Kernel 2: finalize perplexity from the global marginal (640 floats).
// ---------------------------------------------------------------------------
__global__ __launch_bounds__(640)
void finalize(const float* __restrict__ marginal, float* __restrict__ perp_out) {
    __shared__ float terms[640];
    __shared__ float gsum[2];
    const int t = threadIdx.x;

    const float m = marginal[t] * (1.0f / (float)M_ROWS);
    terms[t] = -m * __logf(m + 1e-7f);
    __syncthreads();

    if (t < 128) {
        const int g = t >> 6, lane = t & 63;
        float e = 0.f;
#pragma unroll
        for (int j = 0; j < 5; ++j) e += terms[g * V_CODES + lane + 64 * j];
#pragma unroll
        for (int off = 32; off; off >>= 1) e += __shfl_down(e, off);
        if (lane == 0) gsum[g] = e;
    }
    __syncthreads();
    if (t == 0) perp_out[0] = __expf(gsum[0]) + __expf(gsum[1]);
}

// ---------------------------------------------------------------------------
extern "C" void kernel_launch(void* const* d_in, const int* in_sizes, int n_in,
                              void* d_out, int out_size, void* d_ws, size_t ws_size,
                              hipStream_t stream) {
    (void)in_sizes; (void)n_in; (void)out_size; (void)ws_size;
    const float* hs = (const float*)d_in[0];   // (8,2048,512) f32
    const float* W  = (const float*)d_in[1];   // (512,640)    f32
    const float* bi = (const float*)d_in[2];   // (640,)       f32
    const float* cv = (const float*)d_in[3];   // (1,640,128)  f32
    const float* gu = (const float*)d_in[4];   // (32768,320)  f32
    float* out = (float*)d_out;                // 16384*256 + 1

    // ws: Wt f16 (640 KB) + marginal (640 f32)
    _Float16* Wt       = (_Float16*)d_ws;
    float*    marginal = (float*)(Wt + (size_t)N_COLS * K_DIM);

    prepW<<<321, 256, 0, stream>>>(W, Wt, marginal);
    fused<<<dim3(256, 2), 512, 0, stream>>>(hs, Wt, bi, gu, cv, out, marginal);
    finalize<<<1, 640, 0, stream>>>(marginal, out + (size_t)M_ROWS * 256);
}